// Round 14
// baseline (166.168 us; speedup 1.0000x reference)
//
#include <hip/hip_runtime.h>
#include <hip/hip_fp16.h>

#define GSZ 640
#define NIMG 320
#define MS 102400
#define NC 12
#define BETA_F 13.8551004f
#define TWOPI_F 6.2831855f
// fp16 grid scaling: G is ~1e-9..1e-10 in the reference's un-normalized KB
// convention. Scale by 2^24 ONCE in passA; fold 2^-24 into the tap weights.
#define GSC 16777216.0f
#define GSC_INV 5.9604645e-8f
#define NBLK 400           // 400*256 == MS

// ---------- Bessel I0 (Abramowitz & Stegun 9.8.1 / 9.8.2, rel err < 2e-7) ----------
__device__ __forceinline__ float i0f(float x) {
    float ax = fabsf(x);
    if (ax < 3.75f) {
        float t = ax * (1.0f / 3.75f);
        t *= t;
        return 1.0f + t * (3.5156229f + t * (3.0899424f + t * (1.2067492f +
                     t * (0.2659732f + t * (0.0360768f + t * 0.0045813f)))));
    } else {
        float t = 3.75f / ax;
        float p = 0.39894228f + t * (0.01328592f + t * (0.00225319f + t * (-0.00157565f +
                  t * (0.00916281f + t * (-0.02057706f + t * (0.02635537f +
                  t * (-0.01647633f + t * 0.00392377f)))))));
        return p * expf(ax) / sqrtf(ax);
    }
}

// Kaiser-Bessel kernel, support |u| <= 3 (J=6)
__device__ __forceinline__ float kbval(float u) {
    float mm = fabsf(u) * (1.0f / 3.0f);
    float s = 1.0f - mm * mm;
    s = s > 0.0f ? s : 0.0f;
    float v = i0f(BETA_F * sqrtf(s)) * (1.0f / 6.0f);
    return (mm <= 1.0f) ? v : 0.0f;
}

// image-domain apodization correction at pixel n (0..319).
// __cosf: args <= 4.8 rad, rel err ~1e-6 -- way inside the 0.074 threshold.
__device__ __forceinline__ float apodval(int n) {
    float s = 0.0f;
    #pragma unroll
    for (int j = -3; j <= 3; ++j) {
        s += kbval((float)j) * __cosf((TWOPI_F * (float)j * ((float)n - 160.0f)) / 640.0f);
    }
    return 1.0f / s;
}

__device__ __forceinline__ float2 cmul(float2 a, float2 w) {
    return make_float2(a.x * w.x - a.y * w.y, a.x * w.y + a.y * w.x);
}

// Stockham DIF radix-4 stage: 160 butterflies, call with t < 160.
__device__ __forceinline__ void radix4_stage(const float2* src, float2* dst,
                                             int t, int s, int n) {
    int p = t / s, q = t - p * s;
    int m = n >> 2;
    float2 a0 = src[q + s * p];
    float2 a1 = src[q + s * (p + m)];
    float2 a2 = src[q + s * (p + 2 * m)];
    float2 a3 = src[q + s * (p + 3 * m)];
    float2 e = make_float2(a0.x + a2.x, a0.y + a2.y);
    float2 f = make_float2(a1.x + a3.x, a1.y + a3.y);
    float2 g = make_float2(a0.x - a2.x, a0.y - a2.y);
    float2 h = make_float2(a1.x - a3.x, a1.y - a3.y);
    float2 B0 = make_float2(e.x + f.x, e.y + f.y);
    float2 B2 = make_float2(e.x - f.x, e.y - f.y);
    float2 mih = make_float2(h.y, -h.x);                 // -i*h
    float2 B1 = make_float2(g.x + mih.x, g.y + mih.y);
    float2 B3 = make_float2(g.x - mih.x, g.y - mih.y);
    float ang = (-TWOPI_F) * (float)p / (float)n;
    float s1, c1, s2, c2, s3, c3;
    __sincosf(ang, &s1, &c1);
    __sincosf(2.0f * ang, &s2, &c2);
    __sincosf(3.0f * ang, &s3, &c3);
    dst[q + s * (4 * p)]     = B0;
    dst[q + s * (4 * p + 1)] = cmul(B1, make_float2(c1, s1));
    dst[q + s * (4 * p + 2)] = cmul(B2, make_float2(c2, s2));
    dst[q + s * (4 * p + 3)] = cmul(B3, make_float2(c3, s3));
}

// ---------- 640-point FFT: radix-5, 3x radix-4 (LDS), final radix-2 in regs ----------
__device__ void fft640(float2* bA, float2* bB, int t, float2* olo, float2* ohi) {
    __syncthreads();   // bA ready
    if (t < 128) {
        float2 aj[5];
        #pragma unroll
        for (int j = 0; j < 5; ++j) aj[j] = bA[t + 128 * j];
        const float wr[5] = {1.0f, 0.30901699f, -0.80901699f, -0.80901699f, 0.30901699f};
        const float wi[5] = {0.0f, -0.95105652f, -0.58778525f, 0.58778525f, 0.95105652f};
        #pragma unroll
        for (int r = 0; r < 5; ++r) {
            float br = aj[0].x, bi = aj[0].y;
            #pragma unroll
            for (int j = 1; j < 5; ++j) {
                int k = (j * r) % 5;
                br += aj[j].x * wr[k] - aj[j].y * wi[k];
                bi += aj[j].x * wi[k] + aj[j].y * wr[k];
            }
            float sn, cs;
            __sincosf((-TWOPI_F / 640.0f) * (float)(t * r), &sn, &cs);
            bB[5 * t + r] = cmul(make_float2(br, bi), make_float2(cs, sn));
        }
    }
    __syncthreads();
    if (t < 160) radix4_stage(bB, bA, t, 5, 128);
    __syncthreads();
    if (t < 160) radix4_stage(bA, bB, t, 20, 32);
    __syncthreads();
    if (t < 160) radix4_stage(bB, bA, t, 80, 8);
    __syncthreads();
    float2 a = bA[t], b = bA[t + 320];
    *olo = make_float2(a.x + b.x, a.y + b.y);
    *ohi = make_float2(a.x - b.x, a.y - b.y);
}

// ---------- pass A: row FFT, 2 rows/block; writes R16[c][ri][q] fp16 scaled ----------
__global__ __launch_bounds__(640)
void passA_kernel(const float* __restrict__ img_r, const float* __restrict__ img_i,
                  const float* __restrict__ sm_r, const float* __restrict__ sm_i,
                  unsigned int* __restrict__ R16) {
    __shared__ float2 bA[2][GSZ], bB[2][GSZ];
    int e = threadIdx.x >= 320;
    int t = threadIdx.x - 320 * e;
    int ri = 2 * blockIdx.x + e, c = blockIdx.y;
    int h = (ri < 160) ? ri + 160 : ri - 160;
    int w = (t < 160) ? t + 160 : t - 160;
    float scale = apodval(h) * apodval(w) * (GSC / 640.0f);
    float xr = img_r[h * NIMG + w];
    float xi = img_i[h * NIMG + w];
    float sr = sm_r[(c * NIMG + h) * NIMG + w];
    float si = sm_i[(c * NIMG + h) * NIMG + w];
    float vr = (xr * sr - xi * si) * scale;
    float vi = (xr * si + xi * sr) * scale;
    int vnz = (t < 160) ? t : t + 320;   // ifftshifted column position
    int vz  = (t < 160) ? t + 320 : t;
    bA[e][vnz] = make_float2(vr, vi);
    bA[e][vz]  = make_float2(0.0f, 0.0f);
    float2 lo, hi;
    fft640(bA[e], bB[e], t, &lo, &hi);
    __half2 hlo = __float22half2_rn(lo);
    __half2 hhi = __float22half2_rn(hi);
    unsigned int* out = R16 + (c * 320 + ri) * GSZ;
    out[t]       = *(const unsigned int*)&hlo;
    out[t + 320] = *(const unsigned int*)&hhi;
}

// ---------- pass T: pure uint transpose R16[c][ri][q] -> Rt[c][q][ri] ----------
__global__ __launch_bounds__(256)
void passT_kernel(const unsigned int* __restrict__ R, unsigned int* __restrict__ Rt) {
    __shared__ unsigned int tile[32][33];
    int q0 = blockIdx.x * 32, r0 = blockIdx.y * 32, c = blockIdx.z;
    int tx = threadIdx.x & 31, ty = threadIdx.x >> 5;  // 32 x 8
    #pragma unroll
    for (int k = 0; k < 4; ++k) {
        int r = ty + 8 * k;
        tile[r][tx] = R[(c * 320 + r0 + r) * GSZ + q0 + tx];
    }
    __syncthreads();
    #pragma unroll
    for (int k = 0; k < 4; ++k) {
        int r = ty + 8 * k;  // q_sub
        Rt[(c * GSZ + q0 + r) * 320 + r0 + tx] = tile[tx][r];
    }
}

// ---------- pass B1: column FFT, 2 q/block; fp16 in, fp16 out ----------
__global__ __launch_bounds__(640)
void passB1_kernel(const unsigned int* __restrict__ Rt, unsigned int* __restrict__ F) {
    __shared__ float2 bA[2][GSZ], bB[2][GSZ];
    int e = threadIdx.x >= 320;
    int t = threadIdx.x - 320 * e;
    int q0 = 2 * blockIdx.x, c = blockIdx.y;
    unsigned int raw = Rt[(c * GSZ + q0) * 320 + threadIdx.x];
    float2 val = __half22float2(*(const __half2*)&raw);
    int rnz = (t < 160) ? t : t + 320;
    int rz  = (t < 160) ? t + 320 : t;
    bA[e][rnz] = val;
    bA[e][rz]  = make_float2(0.0f, 0.0f);
    float2 lo, hi;
    fft640(bA[e], bB[e], t, &lo, &hi);
    __half2 hlo = __float22half2_rn(lo);
    __half2 hhi = __float22half2_rn(hi);
    unsigned int* out = F + (c * GSZ + q0 + e) * GSZ;
    out[t]       = *(const unsigned int*)&hlo;
    out[t + 320] = *(const unsigned int*)&hhi;
}

// ---------- pass B2: pure uint shuffle F[c][q][u] -> G[q][u][c] ----------
__global__ __launch_bounds__(320)
void passB2_kernel(const unsigned int* __restrict__ F, unsigned int* __restrict__ G) {
    __shared__ unsigned int Ls[NC][321];
    int q = blockIdx.x, u0 = blockIdx.y * 320, t = threadIdx.x;
    #pragma unroll
    for (int c = 0; c < NC; ++c)
        Ls[c][t] = F[(c * GSZ + q) * GSZ + u0 + t];
    __syncthreads();
    uint4* out4 = (uint4*)(G + (q * GSZ + u0) * NC);  // 960 uint4
    #pragma unroll
    for (int j = 0; j < 3; ++j) {
        int k = t + 320 * j;
        int w = 4 * k;
        uint4 v;
        v.x = Ls[(w)     % 12][(w)     / 12];
        v.y = Ls[(w + 1) % 12][(w + 1) / 12];
        v.z = Ls[(w + 2) % 12][(w + 2) / 12];
        v.w = Ls[(w + 3) % 12][(w + 3) / 12];
        out4[k] = v;
    }
}

// ---------- per-sample tap record, precomputed ONCE (not 6x per sample) ----------
struct __align__(16) TapRec {
    float w1[6];
    float w2[6];                 // pre-multiplied by GSC_INV
    unsigned short iu[6], iv[6]; // wrapped grid indices
};                               // 72B -> padded to 80B

__device__ __forceinline__ void taps(float om, float* w, int* idx) {
    float t = fmodf((om * 640.0f) / TWOPI_F, 640.0f);
    if (t < 0.0f) t += 640.0f;
    float base = floorf(t);
    float frac = t - base;
    int ib = (int)base;
    #pragma unroll
    for (int j = 0; j < 6; ++j) {
        w[j] = kbval(frac + (float)(2 - j));  // u = t - (base + j - 2)
        int k = ib + j - 2;
        if (k < 0) k += GSZ;
        if (k >= GSZ) k -= GSZ;
        idx[j] = k;
    }
}

__global__ __launch_bounds__(256)
void tw_kernel(const float* __restrict__ kt, TapRec* __restrict__ TW) {
    int m = blockIdx.x * 256 + threadIdx.x;   // NBLK*256 == MS
    float w1[6], w2[6];
    int iu[6], iv[6];
    taps(kt[m], w1, iu);
    taps(kt[MS + m], w2, iv);
    TapRec r;
    #pragma unroll
    for (int j = 0; j < 6; ++j) {
        r.w1[j] = w1[j];
        r.w2[j] = w2[j] * GSC_INV;
        r.iu[j] = (unsigned short)iu[j];
        r.iv[j] = (unsigned short)iv[j];
    }
    TW[m] = r;
}

struct __align__(8) h2x2 { __half2 a, b; };  // 2 coils: (re,im),(re,im)

// ---------- interpolation: m-order, 6 lanes/sample, BATCHED gathers ----------
// 12 loads issued per batch (j2-pair) before any use: ~12 outstanding vmem ops
// per wait instead of ~4 (VGPR was 32 -> compiler had no room to batch).
__global__ __launch_bounds__(256)
void interp_kernel(const TapRec* __restrict__ TW, const h2x2* __restrict__ Gp,
                   float2* __restrict__ out) {
    int tid = blockIdx.x * 256 + threadIdx.x;   // 614400 = 2400*256 exactly
    int m = tid / 6;
    int p = tid - 6 * m;                        // coil pair index 0..5
    TapRec r = TW[m];
    float a0r = 0.0f, a0i = 0.0f, a1r = 0.0f, a1i = 0.0f;
    #pragma unroll
    for (int jp = 0; jp < 3; ++jp) {            // j2 = 2*jp, 2*jp+1
        h2x2 g[12];
        #pragma unroll
        for (int k = 0; k < 2; ++k) {
            int rb = (int)r.iv[2 * jp + k] * (GSZ * 6) + p;
            #pragma unroll
            for (int j1 = 0; j1 < 6; ++j1)
                g[6 * k + j1] = Gp[rb + (int)r.iu[j1] * 6];
        }
        #pragma unroll
        for (int k = 0; k < 2; ++k) {
            float b2 = r.w2[2 * jp + k];
            #pragma unroll
            for (int j1 = 0; j1 < 6; ++j1) {
                float2 f0 = __half22float2(g[6 * k + j1].a);
                float2 f1 = __half22float2(g[6 * k + j1].b);
                float ww = b2 * r.w1[j1];
                a0r = fmaf(ww, f0.x, a0r);
                a0i = fmaf(ww, f0.y, a0i);
                a1r = fmaf(ww, f1.x, a1r);
                a1i = fmaf(ww, f1.y, a1i);
            }
        }
    }
    out[(2 * p) * MS + m]     = make_float2(a0r, a0i);
    out[(2 * p + 1) * MS + m] = make_float2(a1r, a1i);
}

extern "C" void kernel_launch(void* const* d_in, const int* in_sizes, int n_in,
                              void* d_out, int out_size, void* d_ws, size_t ws_size,
                              hipStream_t stream) {
    const float* img_r = (const float*)d_in[0];
    const float* img_i = (const float*)d_in[1];
    const float* sm_r  = (const float*)d_in[2];
    const float* sm_i  = (const float*)d_in[3];
    const float* kt    = (const float*)d_in[4];

    // ws layout (~67MB):
    // [R16 9.83M][Rt 9.83M][F 19.66M][G 19.66M][TW 8.2M]
    char* base = (char*)d_ws;
    unsigned int* R16 = (unsigned int*)base;                    // 12*320*640*4
    unsigned int* Rt  = (unsigned int*)(base + 9830400);        // 12*640*320*4
    unsigned int* F   = (unsigned int*)(base + 19660800);       // 12*640*640*4
    unsigned int* G   = (unsigned int*)(base + 39321600);       // 640*640*12*4
    TapRec* TW        = (TapRec*)(base + 58982400);             // 80*102400

    tw_kernel<<<NBLK, 256, 0, stream>>>(kt, TW);
    passA_kernel<<<dim3(160, NC), 640, 0, stream>>>(img_r, img_i, sm_r, sm_i, R16);
    passT_kernel<<<dim3(20, 10, NC), 256, 0, stream>>>(R16, Rt);
    passB1_kernel<<<dim3(320, NC), 640, 0, stream>>>(Rt, F);
    passB2_kernel<<<dim3(GSZ, 2), 320, 0, stream>>>(F, G);
    interp_kernel<<<2400, 256, 0, stream>>>(TW, (const h2x2*)G, (float2*)d_out);
}

// Round 15
// 157.303 us; speedup vs baseline: 1.0564x; 1.0564x over previous
//
#include <hip/hip_runtime.h>
#include <hip/hip_fp16.h>

#define GSZ 640
#define NIMG 320
#define MS 102400
#define NC 12
#define BETA_F 13.8551004f
#define TWOPI_F 6.2831855f
// fp16 grid scaling: G is ~1e-9..1e-10 in the reference's un-normalized KB
// convention. Scale by 2^24 ONCE in passA; fold 2^-24 into the tap weights.
#define GSC 16777216.0f
#define GSC_INV 5.9604645e-8f
#define NBLK 400           // 400*256 == MS

// ---------- Bessel I0 (Abramowitz & Stegun 9.8.1 / 9.8.2, rel err < 2e-7) ----------
__device__ __forceinline__ float i0f(float x) {
    float ax = fabsf(x);
    if (ax < 3.75f) {
        float t = ax * (1.0f / 3.75f);
        t *= t;
        return 1.0f + t * (3.5156229f + t * (3.0899424f + t * (1.2067492f +
                     t * (0.2659732f + t * (0.0360768f + t * 0.0045813f)))));
    } else {
        float t = 3.75f / ax;
        float p = 0.39894228f + t * (0.01328592f + t * (0.00225319f + t * (-0.00157565f +
                  t * (0.00916281f + t * (-0.02057706f + t * (0.02635537f +
                  t * (-0.01647633f + t * 0.00392377f)))))));
        return p * expf(ax) / sqrtf(ax);
    }
}

// Kaiser-Bessel kernel, support |u| <= 3 (J=6)
__device__ __forceinline__ float kbval(float u) {
    float mm = fabsf(u) * (1.0f / 3.0f);
    float s = 1.0f - mm * mm;
    s = s > 0.0f ? s : 0.0f;
    float v = i0f(BETA_F * sqrtf(s)) * (1.0f / 6.0f);
    return (mm <= 1.0f) ? v : 0.0f;
}

__device__ __forceinline__ float2 cmul(float2 a, float2 w) {
    return make_float2(a.x * w.x - a.y * w.y, a.x * w.y + a.y * w.x);
}

// ---------- apod: 320 unique values -- compute ONCE, not per passA thread ----------
__global__ void apod_kernel(float* __restrict__ a) {
    int n = threadIdx.x;  // 320 threads
    float s = 0.0f;
    #pragma unroll
    for (int j = -3; j <= 3; ++j) {
        s += kbval((float)j) * __cosf((TWOPI_F * (float)j * ((float)n - 160.0f)) / 640.0f);
    }
    a[n] = 1.0f / s;
}

// Stockham DIF radix-4 stage with LDS twiddle table. 160 butterflies, t < 160.
// w_n^{kp} = tw[k*p*mult], mult = 640/n; max index 465 < 640.
__device__ __forceinline__ void radix4_stage(const float2* src, float2* dst,
                                             const float2* tw, int t, int s,
                                             int n, int mult) {
    int p = t / s, q = t - p * s;
    int m = n >> 2;
    float2 a0 = src[q + s * p];
    float2 a1 = src[q + s * (p + m)];
    float2 a2 = src[q + s * (p + 2 * m)];
    float2 a3 = src[q + s * (p + 3 * m)];
    float2 e = make_float2(a0.x + a2.x, a0.y + a2.y);
    float2 f = make_float2(a1.x + a3.x, a1.y + a3.y);
    float2 g = make_float2(a0.x - a2.x, a0.y - a2.y);
    float2 h = make_float2(a1.x - a3.x, a1.y - a3.y);
    float2 B0 = make_float2(e.x + f.x, e.y + f.y);
    float2 B2 = make_float2(e.x - f.x, e.y - f.y);
    float2 mih = make_float2(h.y, -h.x);                 // -i*h
    float2 B1 = make_float2(g.x + mih.x, g.y + mih.y);
    float2 B3 = make_float2(g.x - mih.x, g.y - mih.y);
    int pm = p * mult;
    dst[q + s * (4 * p)]     = B0;
    dst[q + s * (4 * p + 1)] = cmul(B1, tw[pm]);
    dst[q + s * (4 * p + 2)] = cmul(B2, tw[2 * pm]);
    dst[q + s * (4 * p + 3)] = cmul(B3, tw[3 * pm]);
}

// ---------- 640-point FFT: radix-5, 3x radix-4 (LDS), final radix-2 in regs ----------
// tw = 640-entry LDS twiddle table, built by caller BEFORE the first barrier here.
__device__ void fft640(float2* bA, float2* bB, const float2* tw, int t,
                       float2* olo, float2* ohi) {
    __syncthreads();   // bA + tw ready
    if (t < 128) {
        float2 aj[5];
        #pragma unroll
        for (int j = 0; j < 5; ++j) aj[j] = bA[t + 128 * j];
        const float wr[5] = {1.0f, 0.30901699f, -0.80901699f, -0.80901699f, 0.30901699f};
        const float wi[5] = {0.0f, -0.95105652f, -0.58778525f, 0.58778525f, 0.95105652f};
        #pragma unroll
        for (int r = 0; r < 5; ++r) {
            float br = aj[0].x, bi = aj[0].y;
            #pragma unroll
            for (int j = 1; j < 5; ++j) {
                int k = (j * r) % 5;
                br += aj[j].x * wr[k] - aj[j].y * wi[k];
                bi += aj[j].x * wi[k] + aj[j].y * wr[k];
            }
            bB[5 * t + r] = cmul(make_float2(br, bi), tw[t * r]);  // idx <= 508
        }
    }
    __syncthreads();
    if (t < 160) radix4_stage(bB, bA, tw, t, 5, 128, 5);
    __syncthreads();
    if (t < 160) radix4_stage(bA, bB, tw, t, 20, 32, 20);
    __syncthreads();
    if (t < 160) radix4_stage(bB, bA, tw, t, 80, 8, 80);
    __syncthreads();
    float2 a = bA[t], b = bA[t + 320];
    *olo = make_float2(a.x + b.x, a.y + b.y);
    *ohi = make_float2(a.x - b.x, a.y - b.y);
}

// ---------- pass A: row FFT, 2 rows/block; writes R16[c][ri][q] fp16 scaled ----------
__global__ __launch_bounds__(640)
void passA_kernel(const float* __restrict__ img_r, const float* __restrict__ img_i,
                  const float* __restrict__ sm_r, const float* __restrict__ sm_i,
                  const float* __restrict__ apod, unsigned int* __restrict__ R16) {
    __shared__ float2 bA[2][GSZ], bB[2][GSZ], tw[GSZ];
    // twiddle table: one entry per thread (640 threads)
    {
        float sn, cs;
        __sincosf((-TWOPI_F / 640.0f) * (float)threadIdx.x, &sn, &cs);
        tw[threadIdx.x] = make_float2(cs, sn);
    }
    int e = threadIdx.x >= 320;
    int t = threadIdx.x - 320 * e;
    int ri = 2 * blockIdx.x + e, c = blockIdx.y;
    int h = (ri < 160) ? ri + 160 : ri - 160;
    int w = (t < 160) ? t + 160 : t - 160;
    float scale = apod[h] * apod[w] * (GSC / 640.0f);
    float xr = img_r[h * NIMG + w];
    float xi = img_i[h * NIMG + w];
    float sr = sm_r[(c * NIMG + h) * NIMG + w];
    float si = sm_i[(c * NIMG + h) * NIMG + w];
    float vr = (xr * sr - xi * si) * scale;
    float vi = (xr * si + xi * sr) * scale;
    int vnz = (t < 160) ? t : t + 320;   // ifftshifted column position
    int vz  = (t < 160) ? t + 320 : t;
    bA[e][vnz] = make_float2(vr, vi);
    bA[e][vz]  = make_float2(0.0f, 0.0f);
    float2 lo, hi;
    fft640(bA[e], bB[e], tw, t, &lo, &hi);
    __half2 hlo = __float22half2_rn(lo);
    __half2 hhi = __float22half2_rn(hi);
    unsigned int* out = R16 + (c * 320 + ri) * GSZ;
    out[t]       = *(const unsigned int*)&hlo;
    out[t + 320] = *(const unsigned int*)&hhi;
}

// ---------- pass T: pure uint transpose R16[c][ri][q] -> Rt[c][q][ri] ----------
__global__ __launch_bounds__(256)
void passT_kernel(const unsigned int* __restrict__ R, unsigned int* __restrict__ Rt) {
    __shared__ unsigned int tile[32][33];
    int q0 = blockIdx.x * 32, r0 = blockIdx.y * 32, c = blockIdx.z;
    int tx = threadIdx.x & 31, ty = threadIdx.x >> 5;  // 32 x 8
    #pragma unroll
    for (int k = 0; k < 4; ++k) {
        int r = ty + 8 * k;
        tile[r][tx] = R[(c * 320 + r0 + r) * GSZ + q0 + tx];
    }
    __syncthreads();
    #pragma unroll
    for (int k = 0; k < 4; ++k) {
        int r = ty + 8 * k;  // q_sub
        Rt[(c * GSZ + q0 + r) * 320 + r0 + tx] = tile[tx][r];
    }
}

// ---------- pass B1: column FFT, 2 q/block; fp16 in, fp16 out ----------
__global__ __launch_bounds__(640)
void passB1_kernel(const unsigned int* __restrict__ Rt, unsigned int* __restrict__ F) {
    __shared__ float2 bA[2][GSZ], bB[2][GSZ], tw[GSZ];
    {
        float sn, cs;
        __sincosf((-TWOPI_F / 640.0f) * (float)threadIdx.x, &sn, &cs);
        tw[threadIdx.x] = make_float2(cs, sn);
    }
    int e = threadIdx.x >= 320;
    int t = threadIdx.x - 320 * e;
    int q0 = 2 * blockIdx.x, c = blockIdx.y;
    unsigned int raw = Rt[(c * GSZ + q0) * 320 + threadIdx.x];
    float2 val = __half22float2(*(const __half2*)&raw);
    int rnz = (t < 160) ? t : t + 320;
    int rz  = (t < 160) ? t + 320 : t;
    bA[e][rnz] = val;
    bA[e][rz]  = make_float2(0.0f, 0.0f);
    float2 lo, hi;
    fft640(bA[e], bB[e], tw, t, &lo, &hi);
    __half2 hlo = __float22half2_rn(lo);
    __half2 hhi = __float22half2_rn(hi);
    unsigned int* out = F + (c * GSZ + q0 + e) * GSZ;
    out[t]       = *(const unsigned int*)&hlo;
    out[t + 320] = *(const unsigned int*)&hhi;
}

// ---------- pass B2: pure uint shuffle F[c][q][u] -> G[q][u][c] ----------
__global__ __launch_bounds__(320)
void passB2_kernel(const unsigned int* __restrict__ F, unsigned int* __restrict__ G) {
    __shared__ unsigned int Ls[NC][321];
    int q = blockIdx.x, u0 = blockIdx.y * 320, t = threadIdx.x;
    #pragma unroll
    for (int c = 0; c < NC; ++c)
        Ls[c][t] = F[(c * GSZ + q) * GSZ + u0 + t];
    __syncthreads();
    uint4* out4 = (uint4*)(G + (q * GSZ + u0) * NC);  // 960 uint4
    #pragma unroll
    for (int j = 0; j < 3; ++j) {
        int k = t + 320 * j;
        int w = 4 * k;
        uint4 v;
        v.x = Ls[(w)     % 12][(w)     / 12];
        v.y = Ls[(w + 1) % 12][(w + 1) / 12];
        v.z = Ls[(w + 2) % 12][(w + 2) / 12];
        v.w = Ls[(w + 3) % 12][(w + 3) / 12];
        out4[k] = v;
    }
}

// ---------- per-sample tap record, precomputed ONCE (not 6x per sample) ----------
struct __align__(16) TapRec {
    float w1[6];
    float w2[6];                 // pre-multiplied by GSC_INV
    unsigned short iu[6], iv[6]; // wrapped grid indices
};                               // 72B -> padded to 80B

__device__ __forceinline__ void taps(float om, float* w, int* idx) {
    float t = fmodf((om * 640.0f) / TWOPI_F, 640.0f);
    if (t < 0.0f) t += 640.0f;
    float base = floorf(t);
    float frac = t - base;
    int ib = (int)base;
    #pragma unroll
    for (int j = 0; j < 6; ++j) {
        w[j] = kbval(frac + (float)(2 - j));  // u = t - (base + j - 2)
        int k = ib + j - 2;
        if (k < 0) k += GSZ;
        if (k >= GSZ) k -= GSZ;
        idx[j] = k;
    }
}

__global__ __launch_bounds__(256)
void tw_kernel(const float* __restrict__ kt, TapRec* __restrict__ TW) {
    int m = blockIdx.x * 256 + threadIdx.x;   // NBLK*256 == MS
    float w1[6], w2[6];
    int iu[6], iv[6];
    taps(kt[m], w1, iu);
    taps(kt[MS + m], w2, iv);
    TapRec r;
    #pragma unroll
    for (int j = 0; j < 6; ++j) {
        r.w1[j] = w1[j];
        r.w2[j] = w2[j] * GSC_INV;
        r.iu[j] = (unsigned short)iu[j];
        r.iv[j] = (unsigned short)iv[j];
    }
    TW[m] = r;
}

struct __align__(8) h2x2 { __half2 a, b; };  // 2 coils: (re,im),(re,im)

// ---------- interpolation: m-order (coalesced out), 6 lanes/sample, taps from TW ----------
__global__ __launch_bounds__(256)
void interp_kernel(const TapRec* __restrict__ TW, const h2x2* __restrict__ Gp,
                   float2* __restrict__ out) {
    int tid = blockIdx.x * 256 + threadIdx.x;   // 614400 = 2400*256 exactly
    int m = tid / 6;
    int p = tid - 6 * m;                        // coil pair index 0..5
    TapRec r = TW[m];
    float a0r = 0.0f, a0i = 0.0f, a1r = 0.0f, a1i = 0.0f;
    #pragma unroll
    for (int j2 = 0; j2 < 6; ++j2) {
        int rb = (int)r.iv[j2] * (GSZ * 6) + p;
        float b2 = r.w2[j2];
        #pragma unroll
        for (int j1 = 0; j1 < 6; ++j1) {
            h2x2 g = Gp[rb + (int)r.iu[j1] * 6];
            float2 f0 = __half22float2(g.a);
            float2 f1 = __half22float2(g.b);
            float ww = b2 * r.w1[j1];
            a0r = fmaf(ww, f0.x, a0r);
            a0i = fmaf(ww, f0.y, a0i);
            a1r = fmaf(ww, f1.x, a1r);
            a1i = fmaf(ww, f1.y, a1i);
        }
    }
    out[(2 * p) * MS + m]     = make_float2(a0r, a0i);
    out[(2 * p + 1) * MS + m] = make_float2(a1r, a1i);
}

extern "C" void kernel_launch(void* const* d_in, const int* in_sizes, int n_in,
                              void* d_out, int out_size, void* d_ws, size_t ws_size,
                              hipStream_t stream) {
    const float* img_r = (const float*)d_in[0];
    const float* img_i = (const float*)d_in[1];
    const float* sm_r  = (const float*)d_in[2];
    const float* sm_i  = (const float*)d_in[3];
    const float* kt    = (const float*)d_in[4];

    // ws layout (~67MB):
    // [R16 9.83M][Rt 9.83M][F 19.66M][G 19.66M][TW 8.2M][apod 1.3K]
    char* base = (char*)d_ws;
    unsigned int* R16 = (unsigned int*)base;                    // 12*320*640*4
    unsigned int* Rt  = (unsigned int*)(base + 9830400);        // 12*640*320*4
    unsigned int* F   = (unsigned int*)(base + 19660800);       // 12*640*640*4
    unsigned int* G   = (unsigned int*)(base + 39321600);       // 640*640*12*4
    TapRec* TW        = (TapRec*)(base + 58982400);             // 80*102400
    float* apod       = (float*)(base + 58982400 + 8192000);    // 320 floats

    apod_kernel<<<1, 320, 0, stream>>>(apod);
    tw_kernel<<<NBLK, 256, 0, stream>>>(kt, TW);
    passA_kernel<<<dim3(160, NC), 640, 0, stream>>>(img_r, img_i, sm_r, sm_i, apod, R16);
    passT_kernel<<<dim3(20, 10, NC), 256, 0, stream>>>(R16, Rt);
    passB1_kernel<<<dim3(320, NC), 640, 0, stream>>>(Rt, F);
    passB2_kernel<<<dim3(GSZ, 2), 320, 0, stream>>>(F, G);
    interp_kernel<<<2400, 256, 0, stream>>>(TW, (const h2x2*)G, (float2*)d_out);
}

// Round 16
// 156.593 us; speedup vs baseline: 1.0611x; 1.0045x over previous
//
#include <hip/hip_runtime.h>
#include <hip/hip_fp16.h>

#define GSZ 640
#define NIMG 320
#define MS 102400
#define NC 12
#define BETA_F 13.8551004f
#define TWOPI_F 6.2831855f
// fp16 grid scaling: G is ~1e-9..1e-10 in the reference's un-normalized KB
// convention. Scale by 2^24 ONCE in passA; fold 2^-24 into the tap weights.
#define GSC 16777216.0f
#define GSC_INV 5.9604645e-8f
#define NBLK 400           // 400*256 == MS

// ---------- Bessel I0 (Abramowitz & Stegun 9.8.1 / 9.8.2, rel err < 2e-7) ----------
__device__ __forceinline__ float i0f(float x) {
    float ax = fabsf(x);
    if (ax < 3.75f) {
        float t = ax * (1.0f / 3.75f);
        t *= t;
        return 1.0f + t * (3.5156229f + t * (3.0899424f + t * (1.2067492f +
                     t * (0.2659732f + t * (0.0360768f + t * 0.0045813f)))));
    } else {
        float t = 3.75f / ax;
        float p = 0.39894228f + t * (0.01328592f + t * (0.00225319f + t * (-0.00157565f +
                  t * (0.00916281f + t * (-0.02057706f + t * (0.02635537f +
                  t * (-0.01647633f + t * 0.00392377f)))))));
        return p * expf(ax) / sqrtf(ax);
    }
}

// Kaiser-Bessel kernel, support |u| <= 3 (J=6)
__device__ __forceinline__ float kbval(float u) {
    float mm = fabsf(u) * (1.0f / 3.0f);
    float s = 1.0f - mm * mm;
    s = s > 0.0f ? s : 0.0f;
    float v = i0f(BETA_F * sqrtf(s)) * (1.0f / 6.0f);
    return (mm <= 1.0f) ? v : 0.0f;
}

__device__ __forceinline__ float2 cmul(float2 a, float2 w) {
    return make_float2(a.x * w.x - a.y * w.y, a.x * w.y + a.y * w.x);
}

// ---------- apod: 320 unique values -- compute ONCE, not per passA thread ----------
__global__ void apod_kernel(float* __restrict__ a) {
    int n = threadIdx.x;  // 320 threads
    float s = 0.0f;
    #pragma unroll
    for (int j = -3; j <= 3; ++j) {
        s += kbval((float)j) * __cosf((TWOPI_F * (float)j * ((float)n - 160.0f)) / 640.0f);
    }
    a[n] = 1.0f / s;
}

// Stockham DIF radix-4 stage with LDS twiddle table. 160 butterflies, t < 160.
__device__ __forceinline__ void radix4_stage(const float2* src, float2* dst,
                                             const float2* tw, int t, int s,
                                             int n, int mult) {
    int p = t / s, q = t - p * s;
    int m = n >> 2;
    float2 a0 = src[q + s * p];
    float2 a1 = src[q + s * (p + m)];
    float2 a2 = src[q + s * (p + 2 * m)];
    float2 a3 = src[q + s * (p + 3 * m)];
    float2 e = make_float2(a0.x + a2.x, a0.y + a2.y);
    float2 f = make_float2(a1.x + a3.x, a1.y + a3.y);
    float2 g = make_float2(a0.x - a2.x, a0.y - a2.y);
    float2 h = make_float2(a1.x - a3.x, a1.y - a3.y);
    float2 B0 = make_float2(e.x + f.x, e.y + f.y);
    float2 B2 = make_float2(e.x - f.x, e.y - f.y);
    float2 mih = make_float2(h.y, -h.x);                 // -i*h
    float2 B1 = make_float2(g.x + mih.x, g.y + mih.y);
    float2 B3 = make_float2(g.x - mih.x, g.y - mih.y);
    int pm = p * mult;
    dst[q + s * (4 * p)]     = B0;
    dst[q + s * (4 * p + 1)] = cmul(B1, tw[pm]);
    dst[q + s * (4 * p + 2)] = cmul(B2, tw[2 * pm]);
    dst[q + s * (4 * p + 3)] = cmul(B3, tw[3 * pm]);
}

// ---------- 640-point FFT: radix-5, 3x radix-4 (LDS), final radix-2 in regs ----------
// tw = 640-entry LDS twiddle table, built by caller BEFORE the first barrier here.
__device__ void fft640(float2* bA, float2* bB, const float2* tw, int t,
                       float2* olo, float2* ohi) {
    __syncthreads();   // bA + tw ready
    if (t < 128) {
        float2 aj[5];
        #pragma unroll
        for (int j = 0; j < 5; ++j) aj[j] = bA[t + 128 * j];
        const float wr[5] = {1.0f, 0.30901699f, -0.80901699f, -0.80901699f, 0.30901699f};
        const float wi[5] = {0.0f, -0.95105652f, -0.58778525f, 0.58778525f, 0.95105652f};
        #pragma unroll
        for (int r = 0; r < 5; ++r) {
            float br = aj[0].x, bi = aj[0].y;
            #pragma unroll
            for (int j = 1; j < 5; ++j) {
                int k = (j * r) % 5;
                br += aj[j].x * wr[k] - aj[j].y * wi[k];
                bi += aj[j].x * wi[k] + aj[j].y * wr[k];
            }
            bB[5 * t + r] = cmul(make_float2(br, bi), tw[t * r]);  // idx <= 508
        }
    }
    __syncthreads();
    if (t < 160) radix4_stage(bB, bA, tw, t, 5, 128, 5);
    __syncthreads();
    if (t < 160) radix4_stage(bA, bB, tw, t, 20, 32, 20);
    __syncthreads();
    if (t < 160) radix4_stage(bB, bA, tw, t, 80, 8, 80);
    __syncthreads();
    float2 a = bA[t], b = bA[t + 320];
    *olo = make_float2(a.x + b.x, a.y + b.y);
    *ohi = make_float2(a.x - b.x, a.y - b.y);
}

// ---------- pass A: row FFT, 2 rows/block; writes R16[c][ri][q] fp16 scaled ----------
__global__ __launch_bounds__(640)
void passA_kernel(const float* __restrict__ img_r, const float* __restrict__ img_i,
                  const float* __restrict__ sm_r, const float* __restrict__ sm_i,
                  const float* __restrict__ apod, unsigned int* __restrict__ R16) {
    __shared__ float2 bA[2][GSZ], bB[2][GSZ], tw[GSZ];
    {
        float sn, cs;
        __sincosf((-TWOPI_F / 640.0f) * (float)threadIdx.x, &sn, &cs);
        tw[threadIdx.x] = make_float2(cs, sn);
    }
    int e = threadIdx.x >= 320;
    int t = threadIdx.x - 320 * e;
    int ri = 2 * blockIdx.x + e, c = blockIdx.y;
    int h = (ri < 160) ? ri + 160 : ri - 160;
    int w = (t < 160) ? t + 160 : t - 160;
    float scale = apod[h] * apod[w] * (GSC / 640.0f);
    float xr = img_r[h * NIMG + w];
    float xi = img_i[h * NIMG + w];
    float sr = sm_r[(c * NIMG + h) * NIMG + w];
    float si = sm_i[(c * NIMG + h) * NIMG + w];
    float vr = (xr * sr - xi * si) * scale;
    float vi = (xr * si + xi * sr) * scale;
    int vnz = (t < 160) ? t : t + 320;   // ifftshifted column position
    int vz  = (t < 160) ? t + 320 : t;
    bA[e][vnz] = make_float2(vr, vi);
    bA[e][vz]  = make_float2(0.0f, 0.0f);
    float2 lo, hi;
    fft640(bA[e], bB[e], tw, t, &lo, &hi);
    __half2 hlo = __float22half2_rn(lo);
    __half2 hhi = __float22half2_rn(hi);
    unsigned int* out = R16 + (c * 320 + ri) * GSZ;
    out[t]       = *(const unsigned int*)&hlo;
    out[t + 320] = *(const unsigned int*)&hhi;
}

// ---------- pass T: pure uint transpose R16[c][ri][q] -> Rt[c][q][ri] ----------
__global__ __launch_bounds__(256)
void passT_kernel(const unsigned int* __restrict__ R, unsigned int* __restrict__ Rt) {
    __shared__ unsigned int tile[32][33];
    int q0 = blockIdx.x * 32, r0 = blockIdx.y * 32, c = blockIdx.z;
    int tx = threadIdx.x & 31, ty = threadIdx.x >> 5;  // 32 x 8
    #pragma unroll
    for (int k = 0; k < 4; ++k) {
        int r = ty + 8 * k;
        tile[r][tx] = R[(c * 320 + r0 + r) * GSZ + q0 + tx];
    }
    __syncthreads();
    #pragma unroll
    for (int k = 0; k < 4; ++k) {
        int r = ty + 8 * k;  // q_sub
        Rt[(c * GSZ + q0 + r) * 320 + r0 + tx] = tile[tx][r];
    }
}

// ---------- pass B1: column FFT, 2 q/block; fp16 in, fp16 out ----------
__global__ __launch_bounds__(640)
void passB1_kernel(const unsigned int* __restrict__ Rt, unsigned int* __restrict__ F) {
    __shared__ float2 bA[2][GSZ], bB[2][GSZ], tw[GSZ];
    {
        float sn, cs;
        __sincosf((-TWOPI_F / 640.0f) * (float)threadIdx.x, &sn, &cs);
        tw[threadIdx.x] = make_float2(cs, sn);
    }
    int e = threadIdx.x >= 320;
    int t = threadIdx.x - 320 * e;
    int q0 = 2 * blockIdx.x, c = blockIdx.y;
    unsigned int raw = Rt[(c * GSZ + q0) * 320 + threadIdx.x];
    float2 val = __half22float2(*(const __half2*)&raw);
    int rnz = (t < 160) ? t : t + 320;
    int rz  = (t < 160) ? t + 320 : t;
    bA[e][rnz] = val;
    bA[e][rz]  = make_float2(0.0f, 0.0f);
    float2 lo, hi;
    fft640(bA[e], bB[e], tw, t, &lo, &hi);
    __half2 hlo = __float22half2_rn(lo);
    __half2 hhi = __float22half2_rn(hi);
    unsigned int* out = F + (c * GSZ + q0 + e) * GSZ;
    out[t]       = *(const unsigned int*)&hlo;
    out[t + 320] = *(const unsigned int*)&hhi;
}

// ---------- pass B2: pure uint shuffle F[c][q][u] -> G[q][u][c] ----------
__global__ __launch_bounds__(320)
void passB2_kernel(const unsigned int* __restrict__ F, unsigned int* __restrict__ G) {
    __shared__ unsigned int Ls[NC][321];
    int q = blockIdx.x, u0 = blockIdx.y * 320, t = threadIdx.x;
    #pragma unroll
    for (int c = 0; c < NC; ++c)
        Ls[c][t] = F[(c * GSZ + q) * GSZ + u0 + t];
    __syncthreads();
    uint4* out4 = (uint4*)(G + (q * GSZ + u0) * NC);  // 960 uint4
    #pragma unroll
    for (int j = 0; j < 3; ++j) {
        int k = t + 320 * j;
        int w = 4 * k;
        uint4 v;
        v.x = Ls[(w)     % 12][(w)     / 12];
        v.y = Ls[(w + 1) % 12][(w + 1) / 12];
        v.z = Ls[(w + 2) % 12][(w + 2) / 12];
        v.w = Ls[(w + 3) % 12][(w + 3) / 12];
        out4[k] = v;
    }
}

// ---------- per-sample tap record, precomputed ONCE (not per lane) ----------
struct __align__(16) TapRec {
    float w1[6];
    float w2[6];                 // pre-multiplied by GSC_INV
    unsigned short iu[6], iv[6]; // wrapped grid indices
};                               // 72B -> padded to 80B

__device__ __forceinline__ void taps(float om, float* w, int* idx) {
    float t = fmodf((om * 640.0f) / TWOPI_F, 640.0f);
    if (t < 0.0f) t += 640.0f;
    float base = floorf(t);
    float frac = t - base;
    int ib = (int)base;
    #pragma unroll
    for (int j = 0; j < 6; ++j) {
        w[j] = kbval(frac + (float)(2 - j));  // u = t - (base + j - 2)
        int k = ib + j - 2;
        if (k < 0) k += GSZ;
        if (k >= GSZ) k -= GSZ;
        idx[j] = k;
    }
}

__global__ __launch_bounds__(256)
void tw_kernel(const float* __restrict__ kt, TapRec* __restrict__ TW) {
    int m = blockIdx.x * 256 + threadIdx.x;   // NBLK*256 == MS
    float w1[6], w2[6];
    int iu[6], iv[6];
    taps(kt[m], w1, iu);
    taps(kt[MS + m], w2, iv);
    TapRec r;
    #pragma unroll
    for (int j = 0; j < 6; ++j) {
        r.w1[j] = w1[j];
        r.w2[j] = w2[j] * GSC_INV;
        r.iu[j] = (unsigned short)iu[j];
        r.iv[j] = (unsigned short)iv[j];
    }
    TW[m] = r;
}

// ---------- interpolation: 3 lanes/sample, 4 coils/lane via float4 gathers ----------
// One (v,u) tap = 48B (12 coils x fp16 cplx); lane p in 0..2 loads bytes
// [16p,16p+16) = coils 4p..4p+3 as ONE float4 (16B-aligned: 48 = 3*16).
// Halves gather-instruction count and wave count vs 6-lane/8B version.
__global__ __launch_bounds__(256)
void interp_kernel(const TapRec* __restrict__ TW, const float4* __restrict__ G4,
                   float2* __restrict__ out) {
    int tid = blockIdx.x * 256 + threadIdx.x;   // 307200 = 1200*256 exactly
    int m = tid / 3;
    int p = tid - 3 * m;                        // coil quad index 0..2
    TapRec r = TW[m];
    float ar[4] = {0.f, 0.f, 0.f, 0.f}, ai[4] = {0.f, 0.f, 0.f, 0.f};
    #pragma unroll
    for (int j2 = 0; j2 < 6; ++j2) {
        int rb = (int)r.iv[j2] * (GSZ * 3) + p;   // float4 units: 3 per (v,u)
        float b2 = r.w2[j2];
        #pragma unroll
        for (int j1 = 0; j1 < 6; ++j1) {
            float4 gq = G4[rb + (int)r.iu[j1] * 3];
            const __half2* h = (const __half2*)&gq;   // 4 x (re,im)
            float ww = b2 * r.w1[j1];
            #pragma unroll
            for (int k = 0; k < 4; ++k) {
                float2 f = __half22float2(h[k]);
                ar[k] = fmaf(ww, f.x, ar[k]);
                ai[k] = fmaf(ww, f.y, ai[k]);
            }
        }
    }
    #pragma unroll
    for (int k = 0; k < 4; ++k)
        out[(4 * p + k) * MS + m] = make_float2(ar[k], ai[k]);
}

extern "C" void kernel_launch(void* const* d_in, const int* in_sizes, int n_in,
                              void* d_out, int out_size, void* d_ws, size_t ws_size,
                              hipStream_t stream) {
    const float* img_r = (const float*)d_in[0];
    const float* img_i = (const float*)d_in[1];
    const float* sm_r  = (const float*)d_in[2];
    const float* sm_i  = (const float*)d_in[3];
    const float* kt    = (const float*)d_in[4];

    // ws layout (~67MB):
    // [R16 9.83M][Rt 9.83M][F 19.66M][G 19.66M][TW 8.2M][apod 1.3K]
    char* base = (char*)d_ws;
    unsigned int* R16 = (unsigned int*)base;                    // 12*320*640*4
    unsigned int* Rt  = (unsigned int*)(base + 9830400);        // 12*640*320*4
    unsigned int* F   = (unsigned int*)(base + 19660800);       // 12*640*640*4
    unsigned int* G   = (unsigned int*)(base + 39321600);       // 640*640*12*4
    TapRec* TW        = (TapRec*)(base + 58982400);             // 80*102400
    float* apod       = (float*)(base + 58982400 + 8192000);    // 320 floats

    apod_kernel<<<1, 320, 0, stream>>>(apod);
    tw_kernel<<<NBLK, 256, 0, stream>>>(kt, TW);
    passA_kernel<<<dim3(160, NC), 640, 0, stream>>>(img_r, img_i, sm_r, sm_i, apod, R16);
    passT_kernel<<<dim3(20, 10, NC), 256, 0, stream>>>(R16, Rt);
    passB1_kernel<<<dim3(320, NC), 640, 0, stream>>>(Rt, F);
    passB2_kernel<<<dim3(GSZ, 2), 320, 0, stream>>>(F, G);
    interp_kernel<<<1200, 256, 0, stream>>>(TW, (const float4*)G, (float2*)d_out);
}

// Round 17
// 154.986 us; speedup vs baseline: 1.0721x; 1.0104x over previous
//
#include <hip/hip_runtime.h>
#include <hip/hip_fp16.h>

#define GSZ 640
#define NIMG 320
#define MS 102400
#define NC 12
#define BETA_F 13.8551004f
#define TWOPI_F 6.2831855f
// fp16 grid scaling: G is ~1e-9..1e-10 in the reference's un-normalized KB
// convention. Scale by 2^24 ONCE in passA; fold 2^-24 into the tap weights.
#define GSC 16777216.0f
#define GSC_INV 5.9604645e-8f
#define NBLK 400           // 400*256 == MS

// ---------- Bessel I0 (Abramowitz & Stegun 9.8.1 / 9.8.2, rel err < 2e-7) ----------
__device__ __forceinline__ float i0f(float x) {
    float ax = fabsf(x);
    if (ax < 3.75f) {
        float t = ax * (1.0f / 3.75f);
        t *= t;
        return 1.0f + t * (3.5156229f + t * (3.0899424f + t * (1.2067492f +
                     t * (0.2659732f + t * (0.0360768f + t * 0.0045813f)))));
    } else {
        float t = 3.75f / ax;
        float p = 0.39894228f + t * (0.01328592f + t * (0.00225319f + t * (-0.00157565f +
                  t * (0.00916281f + t * (-0.02057706f + t * (0.02635537f +
                  t * (-0.01647633f + t * 0.00392377f)))))));
        return p * expf(ax) / sqrtf(ax);
    }
}

// Kaiser-Bessel kernel, support |u| <= 3 (J=6)
__device__ __forceinline__ float kbval(float u) {
    float mm = fabsf(u) * (1.0f / 3.0f);
    float s = 1.0f - mm * mm;
    s = s > 0.0f ? s : 0.0f;
    float v = i0f(BETA_F * sqrtf(s)) * (1.0f / 6.0f);
    return (mm <= 1.0f) ? v : 0.0f;
}

__device__ __forceinline__ float2 cmul(float2 a, float2 w) {
    return make_float2(a.x * w.x - a.y * w.y, a.x * w.y + a.y * w.x);
}

// Stockham DIF radix-4 stage with LDS twiddle table. 160 butterflies, t < 160.
__device__ __forceinline__ void radix4_stage(const float2* src, float2* dst,
                                             const float2* tw, int t, int s,
                                             int n, int mult) {
    int p = t / s, q = t - p * s;
    int m = n >> 2;
    float2 a0 = src[q + s * p];
    float2 a1 = src[q + s * (p + m)];
    float2 a2 = src[q + s * (p + 2 * m)];
    float2 a3 = src[q + s * (p + 3 * m)];
    float2 e = make_float2(a0.x + a2.x, a0.y + a2.y);
    float2 f = make_float2(a1.x + a3.x, a1.y + a3.y);
    float2 g = make_float2(a0.x - a2.x, a0.y - a2.y);
    float2 h = make_float2(a1.x - a3.x, a1.y - a3.y);
    float2 B0 = make_float2(e.x + f.x, e.y + f.y);
    float2 B2 = make_float2(e.x - f.x, e.y - f.y);
    float2 mih = make_float2(h.y, -h.x);                 // -i*h
    float2 B1 = make_float2(g.x + mih.x, g.y + mih.y);
    float2 B3 = make_float2(g.x - mih.x, g.y - mih.y);
    int pm = p * mult;
    dst[q + s * (4 * p)]     = B0;
    dst[q + s * (4 * p + 1)] = cmul(B1, tw[pm]);
    dst[q + s * (4 * p + 2)] = cmul(B2, tw[2 * pm]);
    dst[q + s * (4 * p + 3)] = cmul(B3, tw[3 * pm]);
}

// ---------- 640-point FFT: radix-5, 3x radix-4 (LDS), final radix-2 in regs ----------
// tw = 640-entry LDS twiddle table, built by caller BEFORE the first barrier here.
__device__ void fft640(float2* bA, float2* bB, const float2* tw, int t,
                       float2* olo, float2* ohi) {
    __syncthreads();   // bA + tw ready
    if (t < 128) {
        float2 aj[5];
        #pragma unroll
        for (int j = 0; j < 5; ++j) aj[j] = bA[t + 128 * j];
        const float wr[5] = {1.0f, 0.30901699f, -0.80901699f, -0.80901699f, 0.30901699f};
        const float wi[5] = {0.0f, -0.95105652f, -0.58778525f, 0.58778525f, 0.95105652f};
        #pragma unroll
        for (int r = 0; r < 5; ++r) {
            float br = aj[0].x, bi = aj[0].y;
            #pragma unroll
            for (int j = 1; j < 5; ++j) {
                int k = (j * r) % 5;
                br += aj[j].x * wr[k] - aj[j].y * wi[k];
                bi += aj[j].x * wi[k] + aj[j].y * wr[k];
            }
            bB[5 * t + r] = cmul(make_float2(br, bi), tw[t * r]);  // idx <= 508
        }
    }
    __syncthreads();
    if (t < 160) radix4_stage(bB, bA, tw, t, 5, 128, 5);
    __syncthreads();
    if (t < 160) radix4_stage(bA, bB, tw, t, 20, 32, 20);
    __syncthreads();
    if (t < 160) radix4_stage(bB, bA, tw, t, 80, 8, 80);
    __syncthreads();
    float2 a = bA[t], b = bA[t + 320];
    *olo = make_float2(a.x + b.x, a.y + b.y);
    *ohi = make_float2(a.x - b.x, a.y - b.y);
}

// ---------- pass A: row FFT, 2 rows/block; writes R16[c][ri][q] fp16 scaled ----------
__global__ __launch_bounds__(640)
void passA_kernel(const float* __restrict__ img_r, const float* __restrict__ img_i,
                  const float* __restrict__ sm_r, const float* __restrict__ sm_i,
                  const float* __restrict__ apod, unsigned int* __restrict__ R16) {
    __shared__ float2 bA[2][GSZ], bB[2][GSZ], tw[GSZ];
    {
        float sn, cs;
        __sincosf((-TWOPI_F / 640.0f) * (float)threadIdx.x, &sn, &cs);
        tw[threadIdx.x] = make_float2(cs, sn);
    }
    int e = threadIdx.x >= 320;
    int t = threadIdx.x - 320 * e;
    int ri = 2 * blockIdx.x + e, c = blockIdx.y;
    int h = (ri < 160) ? ri + 160 : ri - 160;
    int w = (t < 160) ? t + 160 : t - 160;
    float scale = apod[h] * apod[w] * (GSC / 640.0f);
    float xr = img_r[h * NIMG + w];
    float xi = img_i[h * NIMG + w];
    float sr = sm_r[(c * NIMG + h) * NIMG + w];
    float si = sm_i[(c * NIMG + h) * NIMG + w];
    float vr = (xr * sr - xi * si) * scale;
    float vi = (xr * si + xi * sr) * scale;
    int vnz = (t < 160) ? t : t + 320;   // ifftshifted column position
    int vz  = (t < 160) ? t + 320 : t;
    bA[e][vnz] = make_float2(vr, vi);
    bA[e][vz]  = make_float2(0.0f, 0.0f);
    float2 lo, hi;
    fft640(bA[e], bB[e], tw, t, &lo, &hi);
    __half2 hlo = __float22half2_rn(lo);
    __half2 hhi = __float22half2_rn(hi);
    unsigned int* out = R16 + (c * 320 + ri) * GSZ;
    out[t]       = *(const unsigned int*)&hlo;
    out[t + 320] = *(const unsigned int*)&hhi;
}

// ---------- pass B1: column FFT, 2 q/block; reads R16 STRIDED (L2-served) ----------
// passT deleted: R16[c][ri][q] read at stride 2560B. Per-c slice = 0.8MB,
// L2-resident while that coil's 320 q-blocks sweep it; both engines' q0/q0+1
// hit the same 64B line. Writes F[c][q][u] coalesced fp16.
__global__ __launch_bounds__(640)
void passB1_kernel(const unsigned int* __restrict__ R16, unsigned int* __restrict__ F) {
    __shared__ float2 bA[2][GSZ], bB[2][GSZ], tw[GSZ];
    {
        float sn, cs;
        __sincosf((-TWOPI_F / 640.0f) * (float)threadIdx.x, &sn, &cs);
        tw[threadIdx.x] = make_float2(cs, sn);
    }
    int e = threadIdx.x >= 320;
    int t = threadIdx.x - 320 * e;
    int q = 2 * blockIdx.x + e, c = blockIdx.y;
    unsigned int raw = R16[(c * 320 + t) * GSZ + q];   // strided gather, L2 hit
    float2 val = __half22float2(*(const __half2*)&raw);
    int rnz = (t < 160) ? t : t + 320;
    int rz  = (t < 160) ? t + 320 : t;
    bA[e][rnz] = val;
    bA[e][rz]  = make_float2(0.0f, 0.0f);
    float2 lo, hi;
    fft640(bA[e], bB[e], tw, t, &lo, &hi);
    __half2 hlo = __float22half2_rn(lo);
    __half2 hhi = __float22half2_rn(hi);
    unsigned int* out = F + (c * GSZ + q) * GSZ;
    out[t]       = *(const unsigned int*)&hlo;
    out[t + 320] = *(const unsigned int*)&hhi;
}

// ---------- pass B2: pure uint shuffle F[c][q][u] -> G[q][u][c] ----------
__global__ __launch_bounds__(320)
void passB2_kernel(const unsigned int* __restrict__ F, unsigned int* __restrict__ G) {
    __shared__ unsigned int Ls[NC][321];
    int q = blockIdx.x, u0 = blockIdx.y * 320, t = threadIdx.x;
    #pragma unroll
    for (int c = 0; c < NC; ++c)
        Ls[c][t] = F[(c * GSZ + q) * GSZ + u0 + t];
    __syncthreads();
    uint4* out4 = (uint4*)(G + (q * GSZ + u0) * NC);  // 960 uint4
    #pragma unroll
    for (int j = 0; j < 3; ++j) {
        int k = t + 320 * j;
        int w = 4 * k;
        uint4 v;
        v.x = Ls[(w)     % 12][(w)     / 12];
        v.y = Ls[(w + 1) % 12][(w + 1) / 12];
        v.z = Ls[(w + 2) % 12][(w + 2) / 12];
        v.w = Ls[(w + 3) % 12][(w + 3) / 12];
        out4[k] = v;
    }
}

// ---------- per-sample tap record, precomputed ONCE (not per lane) ----------
struct __align__(16) TapRec {
    float w1[6];
    float w2[6];                 // pre-multiplied by GSC_INV
    unsigned short iu[6], iv[6]; // wrapped grid indices
};                               // 72B -> padded to 80B

__device__ __forceinline__ void taps(float om, float* w, int* idx) {
    float t = fmodf((om * 640.0f) / TWOPI_F, 640.0f);
    if (t < 0.0f) t += 640.0f;
    float base = floorf(t);
    float frac = t - base;
    int ib = (int)base;
    #pragma unroll
    for (int j = 0; j < 6; ++j) {
        w[j] = kbval(frac + (float)(2 - j));  // u = t - (base + j - 2)
        int k = ib + j - 2;
        if (k < 0) k += GSZ;
        if (k >= GSZ) k -= GSZ;
        idx[j] = k;
    }
}

// tap records for all samples + (block 0) the 320-entry apod table
__global__ __launch_bounds__(256)
void tw_kernel(const float* __restrict__ kt, TapRec* __restrict__ TW,
               float* __restrict__ apod) {
    int m = blockIdx.x * 256 + threadIdx.x;   // NBLK*256 == MS
    if (blockIdx.x == 0) {
        for (int n = threadIdx.x; n < 320; n += 256) {
            float s = 0.0f;
            #pragma unroll
            for (int j = -3; j <= 3; ++j)
                s += kbval((float)j) * __cosf((TWOPI_F * (float)j * ((float)n - 160.0f)) / 640.0f);
            apod[n] = 1.0f / s;
        }
    }
    float w1[6], w2[6];
    int iu[6], iv[6];
    taps(kt[m], w1, iu);
    taps(kt[MS + m], w2, iv);
    TapRec r;
    #pragma unroll
    for (int j = 0; j < 6; ++j) {
        r.w1[j] = w1[j];
        r.w2[j] = w2[j] * GSC_INV;
        r.iu[j] = (unsigned short)iu[j];
        r.iv[j] = (unsigned short)iv[j];
    }
    TW[m] = r;
}

// ---------- interpolation: 3 lanes/sample, 4 coils/lane via float4 gathers ----------
__global__ __launch_bounds__(256)
void interp_kernel(const TapRec* __restrict__ TW, const float4* __restrict__ G4,
                   float2* __restrict__ out) {
    int tid = blockIdx.x * 256 + threadIdx.x;   // 307200 = 1200*256 exactly
    int m = tid / 3;
    int p = tid - 3 * m;                        // coil quad index 0..2
    TapRec r = TW[m];
    float ar[4] = {0.f, 0.f, 0.f, 0.f}, ai[4] = {0.f, 0.f, 0.f, 0.f};
    #pragma unroll
    for (int j2 = 0; j2 < 6; ++j2) {
        int rb = (int)r.iv[j2] * (GSZ * 3) + p;   // float4 units: 3 per (v,u)
        float b2 = r.w2[j2];
        #pragma unroll
        for (int j1 = 0; j1 < 6; ++j1) {
            float4 gq = G4[rb + (int)r.iu[j1] * 3];
            const __half2* h = (const __half2*)&gq;   // 4 x (re,im)
            float ww = b2 * r.w1[j1];
            #pragma unroll
            for (int k = 0; k < 4; ++k) {
                float2 f = __half22float2(h[k]);
                ar[k] = fmaf(ww, f.x, ar[k]);
                ai[k] = fmaf(ww, f.y, ai[k]);
            }
        }
    }
    #pragma unroll
    for (int k = 0; k < 4; ++k)
        out[(4 * p + k) * MS + m] = make_float2(ar[k], ai[k]);
}

extern "C" void kernel_launch(void* const* d_in, const int* in_sizes, int n_in,
                              void* d_out, int out_size, void* d_ws, size_t ws_size,
                              hipStream_t stream) {
    const float* img_r = (const float*)d_in[0];
    const float* img_i = (const float*)d_in[1];
    const float* sm_r  = (const float*)d_in[2];
    const float* sm_i  = (const float*)d_in[3];
    const float* kt    = (const float*)d_in[4];

    // ws layout (~58MB):
    // [R16 9.83M][F 19.66M][G 19.66M][TW 8.2M][apod 1.3K]
    char* base = (char*)d_ws;
    unsigned int* R16 = (unsigned int*)base;                    // 12*320*640*4
    unsigned int* F   = (unsigned int*)(base + 9830400);        // 12*640*640*4
    unsigned int* G   = (unsigned int*)(base + 29491200);       // 640*640*12*4
    TapRec* TW        = (TapRec*)(base + 49152000);             // 80*102400
    float* apod       = (float*)(base + 49152000 + 8192000);    // 320 floats

    tw_kernel<<<NBLK, 256, 0, stream>>>(kt, TW, apod);
    passA_kernel<<<dim3(160, NC), 640, 0, stream>>>(img_r, img_i, sm_r, sm_i, apod, R16);
    passB1_kernel<<<dim3(320, NC), 640, 0, stream>>>(R16, F);
    passB2_kernel<<<dim3(GSZ, 2), 320, 0, stream>>>(F, G);
    interp_kernel<<<1200, 256, 0, stream>>>(TW, (const float4*)G, (float2*)d_out);
}